// Round 1
// 1037.758 us; speedup vs baseline: 1.1363x; 1.1363x over previous
//
#include <hip/hip_runtime.h>
#include <hip/hip_bf16.h>

#define B_ 4
#define S_ 2048
#define D_ 512
#define H_ 8
#define DK_ 64
#define M_ (B_*S_)   // 8192 rows

typedef float f32x4 __attribute__((ext_vector_type(4)));
typedef __bf16 bf16x8 __attribute__((ext_vector_type(8)));
typedef unsigned short u16x8 __attribute__((ext_vector_type(8)));

static __device__ __forceinline__ unsigned short f2bf(float x) {
    return __builtin_bit_cast(unsigned short, __float2bfloat16(x));
}
static __device__ __forceinline__ float bf2f(unsigned short u) {
    return __bfloat162float(__builtin_bit_cast(__hip_bfloat16, u));
}
static __device__ __forceinline__ bf16x8 ldfrag(const unsigned short* p) {
    return __builtin_bit_cast(bf16x8, *(const u16x8*)p);
}

// ---------------------------------------------------------------------------
// MFMA hi/lo-split GEMM: Y = X[M,512] @ W[512,512]^T + bias
//   fp32 operands are split in-register while staging to LDS:
//     hi = top 16 bits (truncate), lo = bf16(f - hi)  [f - hi is exact in fp32]
//   Y ~= Xh@Wh + Xh@Wl + Xl@Wh  (3 MFMAs; dropped Xl@Wl ~ 2^-16 rel)
// 128x128 tile, 4 waves (2x2 of 64x64), K_STEP=32, reg-prefetch next K slab.
// mode 0: Yf32 plain [M,512]
// mode 1: Yhi/Ylo bf16 split, head layout [B,H,S,DK]   (q,k)
// mode 2: Yhi bf16 only, head layout                    (v)
// ---------------------------------------------------------------------------
__global__ __launch_bounds__(256) void proj_mfma_kernel(
    const float* __restrict__ X, const float* __restrict__ W,
    const float* __restrict__ bias, float* __restrict__ Yf32,
    unsigned short* __restrict__ Yhi, unsigned short* __restrict__ Ylo, int mode)
{
    // +8 pad: row stride 80 B (multiple of 16 -> b128 aligned; 20 banks -> 2-way, free)
    __shared__ __align__(16) unsigned short sAh[128][40], sAl[128][40];
    __shared__ __align__(16) unsigned short sBh[128][40], sBl[128][40];

    const int tid  = threadIdx.x;
    const int m0   = blockIdx.x * 128;
    const int n0   = blockIdx.y * 128;
    const int lane = tid & 63, wv = tid >> 6;
    const int quad = lane >> 4, col = lane & 15;
    const int wr   = wv >> 1,  wc  = wv & 1;

    // staging: 2 threads per row; each covers 16 consecutive k (64 B)
    const int srow = tid >> 1;
    const int scol = (tid & 1) * 16;

    const float* pa = X + (size_t)(m0 + srow) * D_ + scol;
    const float* pb = W + (size_t)(n0 + srow) * D_ + scol;

    f32x4 acc[4][4] = {};

    // split 8 fp32 -> hi/lo bf16x8 and store to LDS (b128 writes)
    auto split_write = [&](unsigned short (*Sh)[40], unsigned short (*Sl)[40],
                           const float4& x0, const float4& x1, int coff) {
        float f[8] = {x0.x, x0.y, x0.z, x0.w, x1.x, x1.y, x1.z, x1.w};
        u16x8 h, l;
        #pragma unroll
        for (int j = 0; j < 8; ++j) {
            const unsigned u = __builtin_bit_cast(unsigned, f[j]);
            h[j] = (unsigned short)(u >> 16);
            const float hf = __builtin_bit_cast(float, u & 0xFFFF0000u);
            l[j] = (unsigned short)(__builtin_bit_cast(unsigned, f[j] - hf) >> 16);
        }
        *(u16x8*)&Sh[srow][scol + coff] = h;
        *(u16x8*)&Sl[srow][scol + coff] = l;
    };

    float4 ra[4], rb[4];
    #pragma unroll
    for (int i = 0; i < 4; ++i) {
        ra[i] = *(const float4*)(pa + i * 4);
        rb[i] = *(const float4*)(pb + i * 4);
    }

    for (int kt = 0; kt < D_; kt += 32) {
        split_write(sAh, sAl, ra[0], ra[1], 0);
        split_write(sAh, sAl, ra[2], ra[3], 8);
        split_write(sBh, sBl, rb[0], rb[1], 0);
        split_write(sBh, sBl, rb[2], rb[3], 8);
        __syncthreads();

        // prefetch next K slab into registers (lands under the MFMA phase)
        if (kt + 32 < D_) {
            #pragma unroll
            for (int i = 0; i < 4; ++i) {
                ra[i] = *(const float4*)(pa + kt + 32 + i * 4);
                rb[i] = *(const float4*)(pb + kt + 32 + i * 4);
            }
        }

        bf16x8 ah[4], al[4], bh[4], bl[4];
        #pragma unroll
        for (int i = 0; i < 4; ++i) {
            ah[i] = ldfrag(&sAh[wr * 64 + i * 16 + col][quad * 8]);
            al[i] = ldfrag(&sAl[wr * 64 + i * 16 + col][quad * 8]);
            bh[i] = ldfrag(&sBh[wc * 64 + i * 16 + col][quad * 8]);
            bl[i] = ldfrag(&sBl[wc * 64 + i * 16 + col][quad * 8]);
        }
        #pragma unroll
        for (int mi = 0; mi < 4; ++mi)
            #pragma unroll
            for (int nj = 0; nj < 4; ++nj) {
                acc[mi][nj] = __builtin_amdgcn_mfma_f32_16x16x32_bf16(ah[mi], bh[nj], acc[mi][nj], 0, 0, 0);
                acc[mi][nj] = __builtin_amdgcn_mfma_f32_16x16x32_bf16(al[mi], bh[nj], acc[mi][nj], 0, 0, 0);
                acc[mi][nj] = __builtin_amdgcn_mfma_f32_16x16x32_bf16(ah[mi], bl[nj], acc[mi][nj], 0, 0, 0);
            }
        __syncthreads();
    }

    // epilogue: C/D layout col=lane&15 (n), row=quad*4+r (m)
    #pragma unroll
    for (int nj = 0; nj < 4; ++nj) {
        const int n  = n0 + wc * 64 + nj * 16 + col;
        const float bn = bias[n];
        #pragma unroll
        for (int mi = 0; mi < 4; ++mi) {
            #pragma unroll
            for (int r = 0; r < 4; ++r) {
                const int m  = m0 + wr * 64 + mi * 16 + quad * 4 + r;
                const float vv = acc[mi][nj][r] + bn;
                if (mode == 0) {
                    Yf32[(size_t)m * D_ + n] = vv;
                } else {
                    const int bi = m >> 11;
                    const int si = m & (S_ - 1);
                    const int h  = n >> 6;
                    const int dk = n & 63;
                    const size_t idx = (((size_t)bi * H_ + h) * S_ + si) * DK_ + dk;
                    const unsigned short hi = f2bf(vv);
                    Yhi[idx] = hi;
                    if (mode == 1) Ylo[idx] = f2bf(vv - bf2f(hi));
                }
            }
        }
    }
}

// ---------------------------------------------------------------------------
// Flash-style two-pass MFMA attention (unchanged from previous round).
// Block = 256 thr (4 waves) handles one (b, h, 64-row q-tile).
// Wave w owns q rows [w*16, w*16+16). MFMA 16x16x32 bf16.
// QK^T uses hi/lo bf16 split (3 MFMAs); PV plain bf16.
// C/D layout: col=lane&15, row=(lane>>4)*4+reg. A/B layout: [lane&15][quad*8+j].
// ---------------------------------------------------------------------------
__global__ __launch_bounds__(256) void attn_mfma_kernel(
    const unsigned short* __restrict__ q_hi, const unsigned short* __restrict__ q_lo,
    const unsigned short* __restrict__ k_hi, const unsigned short* __restrict__ k_lo,
    const unsigned short* __restrict__ v_hi, const int* __restrict__ mask,
    float* __restrict__ scores, float* __restrict__ concat)
{
    // +8 pad (16B) keeps b128 alignment; row stride 144B -> 2-way bank alias (free)
    __shared__ __align__(16) unsigned short sQh[64][72], sQl[64][72];
    __shared__ __align__(16) unsigned short sKh[64][72], sKl[64][72];
    __shared__ __align__(16) unsigned short sVt[64][72];  // [dk][kpos]
    __shared__ __align__(16) unsigned short sP[64][72];   // [qrow][kpos]

    const int tid = threadIdx.x;
    const int q0 = blockIdx.x * 64;
    const int h = blockIdx.y, b = blockIdx.z;
    const size_t bh = (size_t)b * H_ + h;
    const int wv = tid >> 6, lane = tid & 63, quad = lane >> 4, col = lane & 15;

    const int sr = tid >> 2, sc = (tid & 3) * 16;   // staging row / col base

    // ---- stage Q tile (hi+lo), once ----
    {
        const u16x8* gh = (const u16x8*)(q_hi + (bh * S_ + q0 + sr) * DK_ + sc);
        const u16x8* gl = (const u16x8*)(q_lo + (bh * S_ + q0 + sr) * DK_ + sc);
        *(u16x8*)&sQh[sr][sc] = gh[0]; *(u16x8*)&sQh[sr][sc + 8] = gh[1];
        *(u16x8*)&sQl[sr][sc] = gl[0]; *(u16x8*)&sQl[sr][sc + 8] = gl[1];
    }

    const int* mbase = mask + (size_t)b * S_ * S_;

    // computes the wave's 16x64 S-tile for k-tile kt into sv[t][r]
    auto compute_svals = [&](int kt, float sv[4][4]) {
        #pragma unroll
        for (int t = 0; t < 4; ++t) {
            f32x4 acc = {0.f, 0.f, 0.f, 0.f};
            #pragma unroll
            for (int kc = 0; kc < 64; kc += 32) {
                bf16x8 ah = ldfrag(&sQh[wv * 16 + col][kc + quad * 8]);
                bf16x8 al = ldfrag(&sQl[wv * 16 + col][kc + quad * 8]);
                bf16x8 bh = ldfrag(&sKh[t * 16 + col][kc + quad * 8]);
                bf16x8 bl = ldfrag(&sKl[t * 16 + col][kc + quad * 8]);
                acc = __builtin_amdgcn_mfma_f32_16x16x32_bf16(ah, bh, acc, 0, 0, 0);
                acc = __builtin_amdgcn_mfma_f32_16x16x32_bf16(ah, bl, acc, 0, 0, 0);
                acc = __builtin_amdgcn_mfma_f32_16x16x32_bf16(al, bh, acc, 0, 0, 0);
            }
            #pragma unroll
            for (int r = 0; r < 4; ++r) {
                const int qg = q0 + wv * 16 + quad * 4 + r;
                const int kg = kt * 64 + t * 16 + col;
                float s = acc[r] * 0.125f;
                if (mbase[(size_t)qg * S_ + kg] == 0) s = -1e9f;
                sv[t][r] = s;
            }
        }
    };

    // ---- pass 1: row max & sum ----
    float m_run[4], l_run[4];
    #pragma unroll
    for (int r = 0; r < 4; ++r) { m_run[r] = -1e30f; l_run[r] = 0.f; }

    for (int kt = 0; kt < 32; ++kt) {
        __syncthreads();
        {
            const u16x8* gh = (const u16x8*)(k_hi + (bh * S_ + kt * 64 + sr) * DK_ + sc);
            const u16x8* gl = (const u16x8*)(k_lo + (bh * S_ + kt * 64 + sr) * DK_ + sc);
            *(u16x8*)&sKh[sr][sc] = gh[0]; *(u16x8*)&sKh[sr][sc + 8] = gh[1];
            *(u16x8*)&sKl[sr][sc] = gl[0]; *(u16x8*)&sKl[sr][sc + 8] = gl[1];
        }
        __syncthreads();
        float sv[4][4];
        compute_svals(kt, sv);
        #pragma unroll
        for (int r = 0; r < 4; ++r) {
            float tm = fmaxf(fmaxf(sv[0][r], sv[1][r]), fmaxf(sv[2][r], sv[3][r]));
            #pragma unroll
            for (int mm = 1; mm < 16; mm <<= 1) tm = fmaxf(tm, __shfl_xor(tm, mm));
            const float nm = fmaxf(m_run[r], tm);
            float ts = __expf(sv[0][r] - nm) + __expf(sv[1][r] - nm)
                     + __expf(sv[2][r] - nm) + __expf(sv[3][r] - nm);
            #pragma unroll
            for (int mm = 1; mm < 16; mm <<= 1) ts += __shfl_xor(ts, mm);
            l_run[r] = l_run[r] * __expf(m_run[r] - nm) + ts;
            m_run[r] = nm;
        }
    }
    float inv_l[4];
    #pragma unroll
    for (int r = 0; r < 4; ++r) inv_l[r] = 1.f / l_run[r];

    // ---- pass 2: recompute S, write scores, accumulate P@V ----
    f32x4 oacc[4] = {};
    for (int kt = 0; kt < 32; ++kt) {
        __syncthreads();
        {
            const u16x8* gh = (const u16x8*)(k_hi + (bh * S_ + kt * 64 + sr) * DK_ + sc);
            const u16x8* gl = (const u16x8*)(k_lo + (bh * S_ + kt * 64 + sr) * DK_ + sc);
            *(u16x8*)&sKh[sr][sc] = gh[0]; *(u16x8*)&sKh[sr][sc + 8] = gh[1];
            *(u16x8*)&sKl[sr][sc] = gl[0]; *(u16x8*)&sKl[sr][sc + 8] = gl[1];
            const u16x8* gv = (const u16x8*)(v_hi + (bh * S_ + kt * 64 + sr) * DK_ + sc);
            u16x8 a0 = gv[0], a1 = gv[1];
            #pragma unroll
            for (int i = 0; i < 8; ++i) { sVt[sc + i][sr] = a0[i]; sVt[sc + 8 + i][sr] = a1[i]; }
        }
        __syncthreads();
        float sv[4][4];
        compute_svals(kt, sv);
        #pragma unroll
        for (int t = 0; t < 4; ++t) {
            #pragma unroll
            for (int r = 0; r < 4; ++r) {
                const int qg = q0 + wv * 16 + quad * 4 + r;
                const int kg = kt * 64 + t * 16 + col;
                const float p = __expf(sv[t][r] - m_run[r]) * inv_l[r];
                scores[(bh * S_ + qg) * S_ + kg] = p;
                sP[wv * 16 + quad * 4 + r][t * 16 + col] = f2bf(p);
            }
        }
        // P@V: sP written & read by the SAME wave only (rows partitioned by wave);
        // per-wave LDS ops are in-order, no cross-wave barrier needed.
        #pragma unroll
        for (int to = 0; to < 4; ++to) {
            #pragma unroll
            for (int kc = 0; kc < 64; kc += 32) {
                bf16x8 a  = ldfrag(&sP[wv * 16 + col][kc + quad * 8]);
                bf16x8 bb = ldfrag(&sVt[to * 16 + col][kc + quad * 8]);
                oacc[to] = __builtin_amdgcn_mfma_f32_16x16x32_bf16(a, bb, oacc[to], 0, 0, 0);
            }
        }
    }

    // ---- epilogue: O -> concat [B,S,D] ----
    #pragma unroll
    for (int to = 0; to < 4; ++to) {
        #pragma unroll
        for (int r = 0; r < 4; ++r) {
            const int qg = q0 + wv * 16 + quad * 4 + r;
            concat[((size_t)b * S_ + qg) * D_ + h * DK_ + to * 16 + col] = oacc[to][r];
        }
    }
}

// ---------------------------------------------------------------------------
extern "C" void kernel_launch(void* const* d_in, const int* in_sizes, int n_in,
                              void* d_out, int out_size, void* d_ws, size_t ws_size,
                              hipStream_t stream) {
    const float* q  = (const float*)d_in[0];
    const float* k  = (const float*)d_in[1];
    const float* v  = (const float*)d_in[2];
    const int* mask = (const int*)d_in[3];
    const float* Wq = (const float*)d_in[4];  const float* bq = (const float*)d_in[5];
    const float* Wk = (const float*)d_in[6];  const float* bk = (const float*)d_in[7];
    const float* Wv = (const float*)d_in[8];  const float* bv = (const float*)d_in[9];
    const float* Wo = (const float*)d_in[10]; const float* bo = (const float*)d_in[11];

    float* out    = (float*)d_out;                 // [B,S,D]
    float* scores = out + (size_t)B_ * S_ * D_;    // [B,H,S,S]

    const size_t NH = (size_t)B_ * H_ * S_ * DK_;  // 4.19M elements
    unsigned short* q_hi = (unsigned short*)d_ws;
    unsigned short* q_lo = q_hi + NH;
    unsigned short* k_hi = q_lo + NH;
    unsigned short* k_lo = k_hi + NH;
    unsigned short* v_hi = k_lo + NH;
    float* concat = (float*)(v_hi + NH);           // [B,S,D] fp32
    // ws use: 5 * 8.39 MB + 16.8 MB ~= 58.7 MB

    dim3 gg(M_ / 128, D_ / 128);   // 64 x 4 = 256 blocks, 1/CU
    proj_mfma_kernel<<<gg, 256, 0, stream>>>(q, Wq, bq, nullptr, q_hi, q_lo, 1);
    proj_mfma_kernel<<<gg, 256, 0, stream>>>(k, Wk, bk, nullptr, k_hi, k_lo, 1);
    proj_mfma_kernel<<<gg, 256, 0, stream>>>(v, Wv, bv, nullptr, v_hi, nullptr, 2);
    attn_mfma_kernel<<<dim3(S_ / 64, H_, B_), 256, 0, stream>>>(
        q_hi, q_lo, k_hi, k_lo, v_hi, mask, scores, concat);
    proj_mfma_kernel<<<gg, 256, 0, stream>>>(concat, Wo, bo, out, nullptr, nullptr, 0);
}

// Round 2
// 1029.554 us; speedup vs baseline: 1.1453x; 1.0080x over previous
//
#include <hip/hip_runtime.h>
#include <hip/hip_bf16.h>

#define B_ 4
#define S_ 2048
#define D_ 512
#define H_ 8
#define DK_ 64
#define M_ (B_*S_)   // 8192 rows

typedef float f32x4 __attribute__((ext_vector_type(4)));
typedef __bf16 bf16x8 __attribute__((ext_vector_type(8)));
typedef unsigned short u16x8 __attribute__((ext_vector_type(8)));

static __device__ __forceinline__ unsigned short f2bf(float x) {
    return __builtin_bit_cast(unsigned short, __float2bfloat16(x));
}
static __device__ __forceinline__ float bf2f(unsigned short u) {
    return __bfloat162float(__builtin_bit_cast(__hip_bfloat16, u));
}
static __device__ __forceinline__ bf16x8 ldfrag(const unsigned short* p) {
    return __builtin_bit_cast(bf16x8, *(const u16x8*)p);
}

// async global->LDS, 16B per lane; LDS dest = wave-uniform base + lane*16
typedef __attribute__((address_space(1))) const unsigned int gu32;
typedef __attribute__((address_space(3))) unsigned int lu32;
static __device__ __forceinline__ void gl_lds16(const unsigned short* g, unsigned short* l) {
    __builtin_amdgcn_global_load_lds((gu32*)g, (lu32*)l, 16, 0, 0);
}

// split 8 fp32 -> hi (truncated bf16) / lo (bf16 of exact residual)
static __device__ __forceinline__ void split8(const float4 x0, const float4 x1,
                                              u16x8& h, u16x8& l) {
    float f[8] = {x0.x, x0.y, x0.z, x0.w, x1.x, x1.y, x1.z, x1.w};
    #pragma unroll
    for (int j = 0; j < 8; ++j) {
        const unsigned u = __builtin_bit_cast(unsigned, f[j]);
        h[j] = (unsigned short)(u >> 16);
        const float hf = __builtin_bit_cast(float, u & 0xFFFF0000u);
        l[j] = (unsigned short)(__builtin_bit_cast(unsigned, f[j] - hf) >> 16);
    }
}

// ---------------------------------------------------------------------------
// Prep: split q,k,v [8192x512] fp32 -> hi/lo bf16 (row-major preserved)
// ---------------------------------------------------------------------------
__global__ __launch_bounds__(256) void split_x3(
    const float* __restrict__ xq, const float* __restrict__ xk, const float* __restrict__ xv,
    unsigned short* __restrict__ qh, unsigned short* __restrict__ qlo,
    unsigned short* __restrict__ kh, unsigned short* __restrict__ klo,
    unsigned short* __restrict__ vh, unsigned short* __restrict__ vlo)
{
    const size_t t = (size_t)blockIdx.x * 256 + threadIdx.x;   // < 524288
    const int z = blockIdx.y;
    const float* in = z == 0 ? xq : z == 1 ? xk : xv;
    unsigned short* oh = z == 0 ? qh : z == 1 ? kh : vh;
    unsigned short* ol = z == 0 ? qlo : z == 1 ? klo : vlo;
    const float4* p = (const float4*)(in + t * 8);
    u16x8 hh, ll;
    split8(p[0], p[1], hh, ll);
    ((u16x8*)oh)[t] = hh;
    ((u16x8*)ol)[t] = ll;
}

// Prep: split Wq,Wk,Wv into concatenated [1536x512] hi/lo; Wo separate
__global__ __launch_bounds__(256) void split_w4(
    const float* __restrict__ Wq, const float* __restrict__ Wk,
    const float* __restrict__ Wv, const float* __restrict__ Wo,
    unsigned short* __restrict__ Wcat_h, unsigned short* __restrict__ Wcat_l,
    unsigned short* __restrict__ Wo_h, unsigned short* __restrict__ Wo_l)
{
    const size_t t = (size_t)blockIdx.x * 256 + threadIdx.x;   // < 32768
    const int z = blockIdx.y;
    const float* in = z == 0 ? Wq : z == 1 ? Wk : z == 2 ? Wv : Wo;
    unsigned short* oh = z < 3 ? Wcat_h + (size_t)z * 262144 : Wo_h;
    unsigned short* ol = z < 3 ? Wcat_l + (size_t)z * 262144 : Wo_l;
    const float4* p = (const float4*)(in + t * 8);
    u16x8 hh, ll;
    split8(p[0], p[1], hh, ll);
    ((u16x8*)oh)[t] = hh;
    ((u16x8*)ol)[t] = ll;
}

// Prep: pack mask int32 [B,S,S] -> bitmask u64 (bit j = mask!=0), 64 cols/word
__global__ __launch_bounds__(256) void mask_pack(
    const int* __restrict__ mask, unsigned long long* __restrict__ bits)
{
    const size_t t = (size_t)blockIdx.x * 256 + threadIdx.x;   // < B*S*S
    const int m = mask[t];
    const unsigned long long w = __ballot(m != 0);
    if ((threadIdx.x & 63) == 0) bits[t >> 6] = w;
}

// ---------------------------------------------------------------------------
// hi/lo-split MFMA GEMM (m97 recipe): Y = X @ W^T + bias
//   Y ~= Xh@Wh + Xl@Wh + Xh@Wl  (3 MFMAs per k-slice)
// BM=128, BN=64, BK=64; 4 waves (2m x 2n), each 64x32 out; global_load_lds
// staging into linear LDS; 2-barrier loop. fused=1: QKV (N=1536, X selected
// per n-block, writes head-layout hi/lo); fused=0: fp32 out (N=512).
// ---------------------------------------------------------------------------
__global__ __launch_bounds__(256) void gemm_hl(
    const unsigned short* __restrict__ qXh, const unsigned short* __restrict__ qXl,
    const unsigned short* __restrict__ kXh, const unsigned short* __restrict__ kXl,
    const unsigned short* __restrict__ vXh, const unsigned short* __restrict__ vXl,
    const unsigned short* __restrict__ Wh, const unsigned short* __restrict__ Wl,
    const float* __restrict__ b0, const float* __restrict__ b1, const float* __restrict__ b2,
    float* __restrict__ Yf32,
    unsigned short* __restrict__ q_hi, unsigned short* __restrict__ q_lo,
    unsigned short* __restrict__ k_hi, unsigned short* __restrict__ k_lo,
    unsigned short* __restrict__ v_hi, int fused)
{
    __shared__ unsigned short sAh[128 * 64], sAl[128 * 64];
    __shared__ unsigned short sBh[64 * 64], sBl[64 * 64];

    const int tid = threadIdx.x;
    const int lane = tid & 63, wv = tid >> 6;
    const int quad = lane >> 4, col = lane & 15;
    const int wm = wv >> 1, wn = wv & 1;
    const int m0 = blockIdx.x * 128;
    const int n0g = blockIdx.y * 64;
    const int mat = fused ? (n0g >> 9) : 0;   // block-uniform
    const unsigned short* Xh = (!fused || mat == 0) ? qXh : (mat == 1 ? kXh : vXh);
    const unsigned short* Xl = (!fused || mat == 0) ? qXl : (mat == 1 ? kXl : vXl);

    const int lr = lane >> 3;        // 0..7  (row within 8-row chunk)
    const int lc = (lane & 7) * 8;   // 0..56 (col elem offset, 16B chunks)

    f32x4 acc[4][2] = {};

    for (int kt = 0; kt < D_; kt += 64) {
        // stage A (128x64 hi+lo) and B (64x64 hi+lo): 12 gl_lds per thread
        #pragma unroll
        for (int i = 0; i < 4; ++i) {
            const int row = wv * 32 + i * 8 + lr;
            gl_lds16(Xh + (size_t)(m0 + row) * D_ + kt + lc, sAh + (size_t)(wv * 32 + i * 8) * 64);
            gl_lds16(Xl + (size_t)(m0 + row) * D_ + kt + lc, sAl + (size_t)(wv * 32 + i * 8) * 64);
        }
        #pragma unroll
        for (int i = 0; i < 2; ++i) {
            const int row = wv * 16 + i * 8 + lr;
            gl_lds16(Wh + (size_t)(n0g + row) * D_ + kt + lc, sBh + (size_t)(wv * 16 + i * 8) * 64);
            gl_lds16(Wl + (size_t)(n0g + row) * D_ + kt + lc, sBl + (size_t)(wv * 16 + i * 8) * 64);
        }
        __syncthreads();   // drains vmcnt -> LDS tile ready

        #pragma unroll
        for (int kc = 0; kc < 64; kc += 32) {
            bf16x8 ah[4], al[4], bh[2], bl[2];
            #pragma unroll
            for (int i = 0; i < 4; ++i) {
                ah[i] = ldfrag(&sAh[(wm * 64 + i * 16 + col) * 64 + kc + quad * 8]);
                al[i] = ldfrag(&sAl[(wm * 64 + i * 16 + col) * 64 + kc + quad * 8]);
            }
            #pragma unroll
            for (int j = 0; j < 2; ++j) {
                bh[j] = ldfrag(&sBh[(wn * 32 + j * 16 + col) * 64 + kc + quad * 8]);
                bl[j] = ldfrag(&sBl[(wn * 32 + j * 16 + col) * 64 + kc + quad * 8]);
            }
            #pragma unroll
            for (int i = 0; i < 4; ++i)
                #pragma unroll
                for (int j = 0; j < 2; ++j) {
                    acc[i][j] = __builtin_amdgcn_mfma_f32_16x16x32_bf16(ah[i], bh[j], acc[i][j], 0, 0, 0);
                    acc[i][j] = __builtin_amdgcn_mfma_f32_16x16x32_bf16(al[i], bh[j], acc[i][j], 0, 0, 0);
                    acc[i][j] = __builtin_amdgcn_mfma_f32_16x16x32_bf16(ah[i], bl[j], acc[i][j], 0, 0, 0);
                }
        }
        __syncthreads();
    }

    // epilogue: C/D layout col=lane&15 (n), row=quad*4+r (m)
    #pragma unroll
    for (int j = 0; j < 2; ++j) {
        const int ng = n0g + wn * 32 + j * 16 + col;
        const int n = fused ? (ng & 511) : ng;
        const float bias = fused ? (mat == 0 ? b0[n] : mat == 1 ? b1[n] : b2[n]) : b0[n];
        #pragma unroll
        for (int i = 0; i < 4; ++i) {
            #pragma unroll
            for (int r = 0; r < 4; ++r) {
                const int m = m0 + wm * 64 + i * 16 + quad * 4 + r;
                const float vv = acc[i][j][r] + bias;
                if (!fused) {
                    Yf32[(size_t)m * D_ + n] = vv;
                } else {
                    const int bi = m >> 11, si = m & (S_ - 1);
                    const int hh = n >> 6, dk = n & 63;
                    const size_t idx = (((size_t)bi * H_ + hh) * S_ + si) * DK_ + dk;
                    const unsigned short hi = f2bf(vv);
                    if (mat == 0)      { q_hi[idx] = hi; q_lo[idx] = f2bf(vv - bf2f(hi)); }
                    else if (mat == 1) { k_hi[idx] = hi; k_lo[idx] = f2bf(vv - bf2f(hi)); }
                    else               { v_hi[idx] = hi; }
                }
            }
        }
    }
}

// ---------------------------------------------------------------------------
// Flash-style two-pass MFMA attention, v2:
//  - Q fragments in registers (LDS 37KB -> 4 blocks/CU)
//  - mask as packed bitwords (4 x 8B L2 loads per tile vs 16 scattered)
//  - T14 async-stage: next tile's K/V global loads issued under compute
//  - epilogue writes concat as hi/lo bf16 (feeds out-proj GEMM directly)
// ---------------------------------------------------------------------------
__global__ __launch_bounds__(256) void attn_mfma_kernel(
    const unsigned short* __restrict__ q_hi, const unsigned short* __restrict__ q_lo,
    const unsigned short* __restrict__ k_hi, const unsigned short* __restrict__ k_lo,
    const unsigned short* __restrict__ v_hi, const unsigned long long* __restrict__ mbits,
    float* __restrict__ scores,
    unsigned short* __restrict__ ch, unsigned short* __restrict__ cl)
{
    // +8 pad (16B) keeps b128 alignment; row stride 144B -> 2-way bank alias (free)
    __shared__ __align__(16) unsigned short sKh[64][72], sKl[64][72];
    __shared__ __align__(16) unsigned short sVt[64][72];  // [dk][kpos]
    __shared__ __align__(16) unsigned short sP[64][72];   // [qrow][kpos]

    const int tid = threadIdx.x;
    const int q0 = blockIdx.x * 64;
    const int h = blockIdx.y, b = blockIdx.z;
    const size_t bh = (size_t)b * H_ + h;
    const int wv = tid >> 6, lane = tid & 63, quad = lane >> 4, col = lane & 15;
    const int sr = tid >> 2, sc = (tid & 3) * 16;   // staging row / col base

    // ---- Q fragments in registers (A-operand: [lane&15=row][quad*8+j=k]) ----
    bf16x8 qh[2], ql[2];
    {
        const size_t qb = (bh * S_ + q0 + wv * 16 + col) * DK_;
        qh[0] = ldfrag(q_hi + qb + quad * 8);
        qh[1] = ldfrag(q_hi + qb + 32 + quad * 8);
        ql[0] = ldfrag(q_lo + qb + quad * 8);
        ql[1] = ldfrag(q_lo + qb + 32 + quad * 8);
    }

    const size_t mrow_base = ((size_t)b * S_ + q0 + wv * 16 + quad * 4) * (S_ / 64);

    // ---- register staging (T14) ----
    u16x8 rkh[2], rkl[2], rv[2];
    auto ld_k = [&](int kt) {
        const u16x8* gh = (const u16x8*)(k_hi + (bh * S_ + kt * 64 + sr) * DK_ + sc);
        const u16x8* gl = (const u16x8*)(k_lo + (bh * S_ + kt * 64 + sr) * DK_ + sc);
        rkh[0] = gh[0]; rkh[1] = gh[1]; rkl[0] = gl[0]; rkl[1] = gl[1];
    };
    auto ld_v = [&](int kt) {
        const u16x8* gv = (const u16x8*)(v_hi + (bh * S_ + kt * 64 + sr) * DK_ + sc);
        rv[0] = gv[0]; rv[1] = gv[1];
    };

    auto compute_svals = [&](const unsigned long long* mw, float sv[4][4]) {
        #pragma unroll
        for (int t = 0; t < 4; ++t) {
            f32x4 acc = {0.f, 0.f, 0.f, 0.f};
            #pragma unroll
            for (int kci = 0; kci < 2; ++kci) {
                bf16x8 bhf = ldfrag(&sKh[t * 16 + col][kci * 32 + quad * 8]);
                bf16x8 blf = ldfrag(&sKl[t * 16 + col][kci * 32 + quad * 8]);
                acc = __builtin_amdgcn_mfma_f32_16x16x32_bf16(qh[kci], bhf, acc, 0, 0, 0);
                acc = __builtin_amdgcn_mfma_f32_16x16x32_bf16(qh[kci], blf, acc, 0, 0, 0);
                acc = __builtin_amdgcn_mfma_f32_16x16x32_bf16(ql[kci], bhf, acc, 0, 0, 0);
            }
            #pragma unroll
            for (int r = 0; r < 4; ++r) {
                float s = acc[r] * 0.125f;
                if (!((mw[r] >> (t * 16 + col)) & 1ull)) s = -1e9f;
                sv[t][r] = s;
            }
        }
    };

    // ---- pass 1: row max & sum ----
    float m_run[4], l_run[4];
    #pragma unroll
    for (int r = 0; r < 4; ++r) { m_run[r] = -1e30f; l_run[r] = 0.f; }

    ld_k(0);
    for (int kt = 0; kt < 32; ++kt) {
        __syncthreads();   // all waves done reading previous tile
        *(u16x8*)&sKh[sr][sc] = rkh[0]; *(u16x8*)&sKh[sr][sc + 8] = rkh[1];
        *(u16x8*)&sKl[sr][sc] = rkl[0]; *(u16x8*)&sKl[sr][sc + 8] = rkl[1];
        __syncthreads();
        if (kt < 31) ld_k(kt + 1);     // latency hides under compute
        unsigned long long mw[4];
        #pragma unroll
        for (int r = 0; r < 4; ++r) mw[r] = mbits[mrow_base + (size_t)r * (S_ / 64) + kt];
        float sv[4][4];
        compute_svals(mw, sv);
        #pragma unroll
        for (int r = 0; r < 4; ++r) {
            float tm = fmaxf(fmaxf(sv[0][r], sv[1][r]), fmaxf(sv[2][r], sv[3][r]));
            #pragma unroll
            for (int mm = 1; mm < 16; mm <<= 1) tm = fmaxf(tm, __shfl_xor(tm, mm));
            const float nm = fmaxf(m_run[r], tm);
            float ts = __expf(sv[0][r] - nm) + __expf(sv[1][r] - nm)
                     + __expf(sv[2][r] - nm) + __expf(sv[3][r] - nm);
            #pragma unroll
            for (int mm = 1; mm < 16; mm <<= 1) ts += __shfl_xor(ts, mm);
            l_run[r] = l_run[r] * __expf(m_run[r] - nm) + ts;
            m_run[r] = nm;
        }
    }
    float inv_l[4];
    #pragma unroll
    for (int r = 0; r < 4; ++r) inv_l[r] = 1.f / l_run[r];

    // ---- pass 2: recompute S, write scores, accumulate P@V ----
    f32x4 oacc[4] = {};
    ld_k(0); ld_v(0);
    for (int kt = 0; kt < 32; ++kt) {
        __syncthreads();
        *(u16x8*)&sKh[sr][sc] = rkh[0]; *(u16x8*)&sKh[sr][sc + 8] = rkh[1];
        *(u16x8*)&sKl[sr][sc] = rkl[0]; *(u16x8*)&sKl[sr][sc + 8] = rkl[1];
        #pragma unroll
        for (int i = 0; i < 8; ++i) { sVt[sc + i][sr] = rv[0][i]; sVt[sc + 8 + i][sr] = rv[1][i]; }
        __syncthreads();
        if (kt < 31) { ld_k(kt + 1); ld_v(kt + 1); }
        unsigned long long mw[4];
        #pragma unroll
        for (int r = 0; r < 4; ++r) mw[r] = mbits[mrow_base + (size_t)r * (S_ / 64) + kt];
        float sv[4][4];
        compute_svals(mw, sv);
        #pragma unroll
        for (int t = 0; t < 4; ++t) {
            #pragma unroll
            for (int r = 0; r < 4; ++r) {
                const int qg = q0 + wv * 16 + quad * 4 + r;
                const int kg = kt * 64 + t * 16 + col;
                const float p = __expf(sv[t][r] - m_run[r]) * inv_l[r];
                scores[(bh * S_ + qg) * S_ + kg] = p;
                sP[wv * 16 + quad * 4 + r][t * 16 + col] = f2bf(p);
            }
        }
        // P@V: sP written & read by the SAME wave only; per-wave LDS ops in-order
        #pragma unroll
        for (int to = 0; to < 4; ++to) {
            #pragma unroll
            for (int kc = 0; kc < 64; kc += 32) {
                bf16x8 a  = ldfrag(&sP[wv * 16 + col][kc + quad * 8]);
                bf16x8 bb = ldfrag(&sVt[to * 16 + col][kc + quad * 8]);
                oacc[to] = __builtin_amdgcn_mfma_f32_16x16x32_bf16(a, bb, oacc[to], 0, 0, 0);
            }
        }
    }

    // ---- epilogue: O -> concat hi/lo bf16 [B,S,D] ----
    #pragma unroll
    for (int to = 0; to < 4; ++to) {
        #pragma unroll
        for (int r = 0; r < 4; ++r) {
            const int qg = q0 + wv * 16 + quad * 4 + r;
            const size_t idx = ((size_t)b * S_ + qg) * D_ + h * DK_ + to * 16 + col;
            const float o = oacc[to][r];
            const unsigned short oh16 = f2bf(o);
            ch[idx] = oh16;
            cl[idx] = f2bf(o - bf2f(oh16));
        }
    }
}

// ---------------------------------------------------------------------------
extern "C" void kernel_launch(void* const* d_in, const int* in_sizes, int n_in,
                              void* d_out, int out_size, void* d_ws, size_t ws_size,
                              hipStream_t stream) {
    const float* q  = (const float*)d_in[0];
    const float* k  = (const float*)d_in[1];
    const float* v  = (const float*)d_in[2];
    const int* mask = (const int*)d_in[3];
    const float* Wq = (const float*)d_in[4];  const float* bq = (const float*)d_in[5];
    const float* Wk = (const float*)d_in[6];  const float* bk = (const float*)d_in[7];
    const float* Wv = (const float*)d_in[8];  const float* bv = (const float*)d_in[9];
    const float* Wo = (const float*)d_in[10]; const float* bo = (const float*)d_in[11];

    float* out    = (float*)d_out;                 // [B,S,D]
    float* scores = out + (size_t)B_ * S_ * D_;    // [B,H,S,S]

    const size_t NH = (size_t)B_ * H_ * S_ * DK_;  // 4.19M elems (== M_*D_)
    unsigned short* W = (unsigned short*)d_ws;
    unsigned short* q_hi = W + 0 * NH;
    unsigned short* q_lo = W + 1 * NH;
    unsigned short* k_hi = W + 2 * NH;
    unsigned short* k_lo = W + 3 * NH;
    unsigned short* v_hi = W + 4 * NH;
    // slots 7..12: X splits (live split->gemm_qkv); concat hi/lo aliases 7/8
    unsigned short* qXh = W + 7 * NH;  unsigned short* qXl = W + 8 * NH;
    unsigned short* kXh = W + 9 * NH;  unsigned short* kXl = W + 10 * NH;
    unsigned short* vXh = W + 11 * NH; unsigned short* vXl = W + 12 * NH;
    unsigned short* cat_h = qXh;       unsigned short* cat_l = qXl;   // reuse after gemm_qkv
    unsigned short* Wcat_h = W + 13 * NH;                 // [1536*512]
    unsigned short* Wcat_l = Wcat_h + 786432;
    unsigned short* Wo_h   = Wcat_l + 786432;             // [512*512]
    unsigned short* Wo_l   = Wo_h + 262144;
    unsigned long long* mbits = (unsigned long long*)(Wo_l + 262144);  // 2MB
    // ws use ~115 MB total

    split_x3<<<dim3(2048, 3), 256, 0, stream>>>(q, k, v, qXh, qXl, kXh, kXl, vXh, vXl);
    split_w4<<<dim3(128, 4), 256, 0, stream>>>(Wq, Wk, Wv, Wo, Wcat_h, Wcat_l, Wo_h, Wo_l);
    mask_pack<<<dim3(65536), 256, 0, stream>>>(mask, mbits);

    // fused QKV projections: N=1536, grid 64x24 = 1536 blocks
    gemm_hl<<<dim3(64, 24), 256, 0, stream>>>(
        qXh, qXl, kXh, kXl, vXh, vXl, Wcat_h, Wcat_l, bq, bk, bv,
        nullptr, q_hi, q_lo, k_hi, k_lo, v_hi, 1);

    attn_mfma_kernel<<<dim3(S_ / 64, H_, B_), 256, 0, stream>>>(
        q_hi, q_lo, k_hi, k_lo, v_hi, mbits, scores, cat_h, cat_l);

    // output projection: N=512, fp32 out
    gemm_hl<<<dim3(64, 8), 256, 0, stream>>>(
        cat_h, cat_l, nullptr, nullptr, nullptr, nullptr, Wo_h, Wo_l, bo, nullptr, nullptr,
        out, nullptr, nullptr, nullptr, nullptr, nullptr, 0);
}

// Round 3
// 987.956 us; speedup vs baseline: 1.1935x; 1.0421x over previous
//
#include <hip/hip_runtime.h>
#include <hip/hip_bf16.h>

#define B_ 4
#define S_ 2048
#define D_ 512
#define H_ 8
#define DK_ 64
#define M_ (B_*S_)   // 8192 rows

typedef float f32x4 __attribute__((ext_vector_type(4)));
typedef __bf16 bf16x8 __attribute__((ext_vector_type(8)));
typedef unsigned short u16x8 __attribute__((ext_vector_type(8)));

static __device__ __forceinline__ unsigned short f2bf(float x) {
    return __builtin_bit_cast(unsigned short, __float2bfloat16(x));
}
static __device__ __forceinline__ float bf2f(unsigned short u) {
    return __bfloat162float(__builtin_bit_cast(__hip_bfloat16, u));
}
static __device__ __forceinline__ bf16x8 ldfrag(const unsigned short* p) {
    return __builtin_bit_cast(bf16x8, *(const u16x8*)p);
}

// async global->LDS, 16B per lane; LDS dest = wave-uniform base + lane*16
typedef __attribute__((address_space(1))) const unsigned int gu32;
typedef __attribute__((address_space(3))) unsigned int lu32;
static __device__ __forceinline__ void gl_lds16(const unsigned short* g, unsigned short* l) {
    __builtin_amdgcn_global_load_lds((gu32*)g, (lu32*)l, 16, 0, 0);
}

// split 8 fp32 -> hi (truncated bf16) / lo (bf16 of exact residual)
static __device__ __forceinline__ void split8(const float4 x0, const float4 x1,
                                              u16x8& h, u16x8& l) {
    float f[8] = {x0.x, x0.y, x0.z, x0.w, x1.x, x1.y, x1.z, x1.w};
    #pragma unroll
    for (int j = 0; j < 8; ++j) {
        const unsigned u = __builtin_bit_cast(unsigned, f[j]);
        h[j] = (unsigned short)(u >> 16);
        const float hf = __builtin_bit_cast(float, u & 0xFFFF0000u);
        l[j] = (unsigned short)(__builtin_bit_cast(unsigned, f[j] - hf) >> 16);
    }
}

// ---------------------------------------------------------------------------
// Prep: split q,k,v [8192x512] fp32 -> hi/lo bf16 (row-major preserved)
// ---------------------------------------------------------------------------
__global__ __launch_bounds__(256) void split_x3(
    const float* __restrict__ xq, const float* __restrict__ xk, const float* __restrict__ xv,
    unsigned short* __restrict__ qh, unsigned short* __restrict__ qlo,
    unsigned short* __restrict__ kh, unsigned short* __restrict__ klo,
    unsigned short* __restrict__ vh, unsigned short* __restrict__ vlo)
{
    const size_t t = (size_t)blockIdx.x * 256 + threadIdx.x;   // < 524288
    const int z = blockIdx.y;
    const float* in = z == 0 ? xq : z == 1 ? xk : xv;
    unsigned short* oh = z == 0 ? qh : z == 1 ? kh : vh;
    unsigned short* ol = z == 0 ? qlo : z == 1 ? klo : vlo;
    const float4* p = (const float4*)(in + t * 8);
    u16x8 hh, ll;
    split8(p[0], p[1], hh, ll);
    ((u16x8*)oh)[t] = hh;
    ((u16x8*)ol)[t] = ll;
}

// Prep: split Wq,Wk,Wv into concatenated [1536x512] hi/lo; Wo separate
__global__ __launch_bounds__(256) void split_w4(
    const float* __restrict__ Wq, const float* __restrict__ Wk,
    const float* __restrict__ Wv, const float* __restrict__ Wo,
    unsigned short* __restrict__ Wcat_h, unsigned short* __restrict__ Wcat_l,
    unsigned short* __restrict__ Wo_h, unsigned short* __restrict__ Wo_l)
{
    const size_t t = (size_t)blockIdx.x * 256 + threadIdx.x;   // < 32768
    const int z = blockIdx.y;
    const float* in = z == 0 ? Wq : z == 1 ? Wk : z == 2 ? Wv : Wo;
    unsigned short* oh = z < 3 ? Wcat_h + (size_t)z * 262144 : Wo_h;
    unsigned short* ol = z < 3 ? Wcat_l + (size_t)z * 262144 : Wo_l;
    const float4* p = (const float4*)(in + t * 8);
    u16x8 hh, ll;
    split8(p[0], p[1], hh, ll);
    ((u16x8*)oh)[t] = hh;
    ((u16x8*)ol)[t] = ll;
}

// Prep: pack mask int32 [B,S,S] -> bitmask u64 (bit j = mask!=0), 64 cols/word
__global__ __launch_bounds__(256) void mask_pack(
    const int* __restrict__ mask, unsigned long long* __restrict__ bits)
{
    const size_t t = (size_t)blockIdx.x * 256 + threadIdx.x;   // < B*S*S
    const int m = mask[t];
    const unsigned long long w = __ballot(m != 0);
    if ((threadIdx.x & 63) == 0) bits[t >> 6] = w;
}

// ---------------------------------------------------------------------------
// hi/lo-split MFMA GEMM v3: Y = X @ W^T + bias
//   Y ~= Xh@Wh + Xl@Wh + Xh@Wl (3 MFMAs per k-slice; dropped Xl@Wl ~ 2^-16)
// 128x128 tile, BK=32, 16 K-steps. Double-buffered LDS (64KB, 2 blocks/CU);
// T3 minimum-2-phase: STAGE(next) issued BEFORE compute, one barrier/step so
// the global_load_lds latency hides under the 48-MFMA phase.
// LDS chunk-swizzle (rule 21 both-sides): gl_lds dest linear; global SOURCE
// pre-swizzled per 16B chunk (c ^ ((row>>1)&3)); ds_read applies same XOR.
// Cuts the A/B fragment read from 8-way to 2-way bank conflict.
// fused=1: QKV (N=1536, X selected per n-block, head-layout hi/lo out)
// fused=0: out-proj (N=512, fp32 out)
// ---------------------------------------------------------------------------
#define GBK 32
__global__ __launch_bounds__(256, 2) void gemm_hl(
    const unsigned short* __restrict__ qXh, const unsigned short* __restrict__ qXl,
    const unsigned short* __restrict__ kXh, const unsigned short* __restrict__ kXl,
    const unsigned short* __restrict__ vXh, const unsigned short* __restrict__ vXl,
    const unsigned short* __restrict__ Wh, const unsigned short* __restrict__ Wl,
    const float* __restrict__ b0, const float* __restrict__ b1, const float* __restrict__ b2,
    float* __restrict__ Yf32,
    unsigned short* __restrict__ q_hi, unsigned short* __restrict__ q_lo,
    unsigned short* __restrict__ k_hi, unsigned short* __restrict__ k_lo,
    unsigned short* __restrict__ v_hi, int fused)
{
    // [buf][arr][128*32] arr: 0=Ah 1=Al 2=Bh 3=Bl   (64 KB total)
    __shared__ __align__(16) unsigned short lds[2][4][128 * GBK];

    const int tid = threadIdx.x;
    const int lane = tid & 63, wv = tid >> 6;
    const int quad = lane >> 4, col = lane & 15;
    const int wm = wv >> 1, wn = wv & 1;
    const int m0 = blockIdx.x * 128;
    const int n0g = blockIdx.y * 128;
    const int mat = fused ? (n0g >> 9) : 0;   // block-uniform
    const unsigned short* Xh = (!fused || mat == 0) ? qXh : (mat == 1 ? kXh : vXh);
    const unsigned short* Xl = (!fused || mat == 0) ? qXl : (mat == 1 ? kXl : vXl);

    // staging lane map: 1024B gl_lds = 16 rows x 64B; lane l -> row l>>2,
    // LDS 16B slot l&3; source chunk pre-swizzled: (l&3) ^ ((l>>3)&3)
    const int rsub = lane >> 2;
    const int csw = (((lane & 3) ^ ((lane >> 3) & 3))) * 8;   // elem offset

    f32x4 acc[4][4] = {};

    auto STAGE = [&](int t, int buf) {
        const int kt = t * GBK;
        #pragma unroll
        for (int i = 0; i < 2; ++i) {
            const int r0 = wv * 32 + i * 16;           // wave-uniform row base
            gl_lds16(Xh + (size_t)(m0 + r0 + rsub) * D_ + kt + csw, &lds[buf][0][r0 * GBK]);
            gl_lds16(Xl + (size_t)(m0 + r0 + rsub) * D_ + kt + csw, &lds[buf][1][r0 * GBK]);
            gl_lds16(Wh + (size_t)(n0g + r0 + rsub) * D_ + kt + csw, &lds[buf][2][r0 * GBK]);
            gl_lds16(Wl + (size_t)(n0g + r0 + rsub) * D_ + kt + csw, &lds[buf][3][r0 * GBK]);
        }
    };

    auto COMPUTE = [&](int buf) {
        bf16x8 ah[4], al[4], bh[4], bl[4];
        #pragma unroll
        for (int i = 0; i < 4; ++i) {
            const int ra = wm * 64 + i * 16 + col;
            const int ca = (quad ^ ((ra >> 1) & 3)) * 8;   // swizzled chunk
            ah[i] = ldfrag(&lds[buf][0][ra * GBK + ca]);
            al[i] = ldfrag(&lds[buf][1][ra * GBK + ca]);
            const int rb = wn * 64 + i * 16 + col;
            const int cb = (quad ^ ((rb >> 1) & 3)) * 8;
            bh[i] = ldfrag(&lds[buf][2][rb * GBK + cb]);
            bl[i] = ldfrag(&lds[buf][3][rb * GBK + cb]);
        }
        __builtin_amdgcn_s_setprio(1);
        #pragma unroll
        for (int i = 0; i < 4; ++i)
            #pragma unroll
            for (int j = 0; j < 4; ++j) {
                acc[i][j] = __builtin_amdgcn_mfma_f32_16x16x32_bf16(ah[i], bh[j], acc[i][j], 0, 0, 0);
                acc[i][j] = __builtin_amdgcn_mfma_f32_16x16x32_bf16(al[i], bh[j], acc[i][j], 0, 0, 0);
                acc[i][j] = __builtin_amdgcn_mfma_f32_16x16x32_bf16(ah[i], bl[j], acc[i][j], 0, 0, 0);
            }
        __builtin_amdgcn_s_setprio(0);
    };

    STAGE(0, 0);
    __syncthreads();                 // implicit vmcnt(0): buf0 ready
    int cur = 0;
    for (int t = 0; t < 16; ++t) {
        if (t < 15) STAGE(t + 1, cur ^ 1);      // issue early; hides under MFMA
        __builtin_amdgcn_sched_barrier(0);      // keep stage issue ahead of compute
        COMPUTE(cur);
        if (t < 15) { __syncthreads(); cur ^= 1; }   // drain vmcnt -> next buf ready
    }

    // epilogue: C/D layout col=lane&15 (n), row=quad*4+r (m)
    #pragma unroll
    for (int j = 0; j < 4; ++j) {
        const int ng = n0g + wn * 64 + j * 16 + col;
        const int n = fused ? (ng & 511) : ng;
        const float bias = fused ? (mat == 0 ? b0[n] : mat == 1 ? b1[n] : b2[n]) : b0[n];
        #pragma unroll
        for (int i = 0; i < 4; ++i) {
            #pragma unroll
            for (int r = 0; r < 4; ++r) {
                const int m = m0 + wm * 64 + i * 16 + quad * 4 + r;
                const float vv = acc[i][j][r] + bias;
                if (!fused) {
                    Yf32[(size_t)m * D_ + n] = vv;
                } else {
                    const int bi = m >> 11, si = m & (S_ - 1);
                    const int hh = n >> 6, dk = n & 63;
                    const size_t idx = (((size_t)bi * H_ + hh) * S_ + si) * DK_ + dk;
                    const unsigned short hi = f2bf(vv);
                    if (mat == 0)      { q_hi[idx] = hi; q_lo[idx] = f2bf(vv - bf2f(hi)); }
                    else if (mat == 1) { k_hi[idx] = hi; k_lo[idx] = f2bf(vv - bf2f(hi)); }
                    else               { v_hi[idx] = hi; }
                }
            }
        }
    }
}

// ---------------------------------------------------------------------------
// Flash-style two-pass MFMA attention, v3:
//  - Q fragments in registers; mask as packed bitwords; T14 async K/V staging
//  - NEW: coalesced scores write. After QK^T the K LDS tile is dead; a fp32
//    [64][68] buffer aliases it. p is transposed through LDS and written as
//    8-row x 128B-contiguous float4 bursts (halves scores write traffic).
//  - setprio(1) around MFMA clusters (T5)
// ---------------------------------------------------------------------------
__global__ __launch_bounds__(256) void attn_mfma_kernel(
    const unsigned short* __restrict__ q_hi, const unsigned short* __restrict__ q_lo,
    const unsigned short* __restrict__ k_hi, const unsigned short* __restrict__ k_lo,
    const unsigned short* __restrict__ v_hi, const unsigned long long* __restrict__ mbits,
    float* __restrict__ scores,
    unsigned short* __restrict__ ch, unsigned short* __restrict__ cl)
{
    // +8 pad (16B) keeps b128 alignment; row stride 144B -> 2-way bank alias (free)
    __shared__ __align__(16) unsigned short sK2[2][64][72];   // [0]=hi [1]=lo
    __shared__ __align__(16) unsigned short sVt[64][72];      // [dk][kpos]
    __shared__ __align__(16) unsigned short sP[64][72];       // [qrow][kpos]

    const int tid = threadIdx.x;
    const int q0 = blockIdx.x * 64;
    const int h = blockIdx.y, b = blockIdx.z;
    const size_t bh = (size_t)b * H_ + h;
    const int wv = tid >> 6, lane = tid & 63, quad = lane >> 4, col = lane & 15;
    const int sr = tid >> 2, sc = (tid & 3) * 16;   // staging row / col base

    // fp32 p-tile aliased over the (dead-after-QK^T) K tile: 64 x 68 f32 = 17.4KB <= 18.4KB
    float* sPF = (float*)&sK2[0][0][0];

    // ---- Q fragments in registers (A-operand: [lane&15=row][quad*8+j=k]) ----
    bf16x8 qh[2], ql[2];
    {
        const size_t qb = (bh * S_ + q0 + wv * 16 + col) * DK_;
        qh[0] = ldfrag(q_hi + qb + quad * 8);
        qh[1] = ldfrag(q_hi + qb + 32 + quad * 8);
        ql[0] = ldfrag(q_lo + qb + quad * 8);
        ql[1] = ldfrag(q_lo + qb + 32 + quad * 8);
    }

    const size_t mrow_base = ((size_t)b * S_ + q0 + wv * 16 + quad * 4) * (S_ / 64);

    // ---- register staging (T14) ----
    u16x8 rkh[2], rkl[2], rv[2];
    auto ld_k = [&](int kt) {
        const u16x8* gh = (const u16x8*)(k_hi + (bh * S_ + kt * 64 + sr) * DK_ + sc);
        const u16x8* gl = (const u16x8*)(k_lo + (bh * S_ + kt * 64 + sr) * DK_ + sc);
        rkh[0] = gh[0]; rkh[1] = gh[1]; rkl[0] = gl[0]; rkl[1] = gl[1];
    };
    auto ld_v = [&](int kt) {
        const u16x8* gv = (const u16x8*)(v_hi + (bh * S_ + kt * 64 + sr) * DK_ + sc);
        rv[0] = gv[0]; rv[1] = gv[1];
    };

    auto compute_svals = [&](const unsigned long long* mw, float sv[4][4]) {
        #pragma unroll
        for (int t = 0; t < 4; ++t) {
            f32x4 acc = {0.f, 0.f, 0.f, 0.f};
            __builtin_amdgcn_s_setprio(1);
            #pragma unroll
            for (int kci = 0; kci < 2; ++kci) {
                bf16x8 bhf = ldfrag(&sK2[0][t * 16 + col][kci * 32 + quad * 8]);
                bf16x8 blf = ldfrag(&sK2[1][t * 16 + col][kci * 32 + quad * 8]);
                acc = __builtin_amdgcn_mfma_f32_16x16x32_bf16(qh[kci], bhf, acc, 0, 0, 0);
                acc = __builtin_amdgcn_mfma_f32_16x16x32_bf16(qh[kci], blf, acc, 0, 0, 0);
                acc = __builtin_amdgcn_mfma_f32_16x16x32_bf16(ql[kci], bhf, acc, 0, 0, 0);
            }
            __builtin_amdgcn_s_setprio(0);
            #pragma unroll
            for (int r = 0; r < 4; ++r) {
                float s = acc[r] * 0.125f;
                if (!((mw[r] >> (t * 16 + col)) & 1ull)) s = -1e9f;
                sv[t][r] = s;
            }
        }
    };

    // ---- pass 1: row max & sum ----
    float m_run[4], l_run[4];
    #pragma unroll
    for (int r = 0; r < 4; ++r) { m_run[r] = -1e30f; l_run[r] = 0.f; }

    ld_k(0);
    for (int kt = 0; kt < 32; ++kt) {
        __syncthreads();   // all waves done reading previous tile
        *(u16x8*)&sK2[0][sr][sc] = rkh[0]; *(u16x8*)&sK2[0][sr][sc + 8] = rkh[1];
        *(u16x8*)&sK2[1][sr][sc] = rkl[0]; *(u16x8*)&sK2[1][sr][sc + 8] = rkl[1];
        __syncthreads();
        if (kt < 31) ld_k(kt + 1);     // latency hides under compute
        unsigned long long mw[4];
        #pragma unroll
        for (int r = 0; r < 4; ++r) mw[r] = mbits[mrow_base + (size_t)r * (S_ / 64) + kt];
        float sv[4][4];
        compute_svals(mw, sv);
        #pragma unroll
        for (int r = 0; r < 4; ++r) {
            float tm = fmaxf(fmaxf(sv[0][r], sv[1][r]), fmaxf(sv[2][r], sv[3][r]));
            #pragma unroll
            for (int mm = 1; mm < 16; mm <<= 1) tm = fmaxf(tm, __shfl_xor(tm, mm));
            const float nm = fmaxf(m_run[r], tm);
            float ts = __expf(sv[0][r] - nm) + __expf(sv[1][r] - nm)
                     + __expf(sv[2][r] - nm) + __expf(sv[3][r] - nm);
            #pragma unroll
            for (int mm = 1; mm < 16; mm <<= 1) ts += __shfl_xor(ts, mm);
            l_run[r] = l_run[r] * __expf(m_run[r] - nm) + ts;
            m_run[r] = nm;
        }
    }
    float inv_l[4];
    #pragma unroll
    for (int r = 0; r < 4; ++r) inv_l[r] = 1.f / l_run[r];

    // ---- pass 2: recompute S, write scores (coalesced), accumulate P@V ----
    f32x4 oacc[4] = {};
    ld_k(0); ld_v(0);
    for (int kt = 0; kt < 32; ++kt) {
        __syncthreads();
        *(u16x8*)&sK2[0][sr][sc] = rkh[0]; *(u16x8*)&sK2[0][sr][sc + 8] = rkh[1];
        *(u16x8*)&sK2[1][sr][sc] = rkl[0]; *(u16x8*)&sK2[1][sr][sc + 8] = rkl[1];
        #pragma unroll
        for (int i = 0; i < 8; ++i) { sVt[sc + i][sr] = rv[0][i]; sVt[sc + 8 + i][sr] = rv[1][i]; }
        __syncthreads();
        if (kt < 31) { ld_k(kt + 1); ld_v(kt + 1); }
        unsigned long long mw[4];
        #pragma unroll
        for (int r = 0; r < 4; ++r) mw[r] = mbits[mrow_base + (size_t)r * (S_ / 64) + kt];
        float sv[4][4];
        compute_svals(mw, sv);
        float pv[4][4];
        #pragma unroll
        for (int t = 0; t < 4; ++t) {
            #pragma unroll
            for (int r = 0; r < 4; ++r) {
                const float p = __expf(sv[t][r] - m_run[r]) * inv_l[r];
                pv[t][r] = p;
                sP[wv * 16 + quad * 4 + r][t * 16 + col] = f2bf(p);
            }
        }
        // K tile now dead for this iteration; all waves must be done reading it
        __syncthreads();
        #pragma unroll
        for (int t = 0; t < 4; ++t)
            #pragma unroll
            for (int r = 0; r < 4; ++r)
                sPF[(wv * 16 + quad * 4 + r) * 68 + t * 16 + col] = pv[t][r];
        // coalesced write: own 16 rows, 8 rows x 128B contiguous per instr
        #pragma unroll
        for (int rg = 0; rg < 2; ++rg)
            #pragma unroll
            for (int hf = 0; hf < 2; ++hf) {
                const int rl = wv * 16 + rg * 8 + (lane >> 3);
                const int cf = hf * 32 + (lane & 7) * 4;
                const float4 pw = *(const float4*)&sPF[rl * 68 + cf];
                *(float4*)&scores[(bh * S_ + q0 + rl) * S_ + kt * 64 + cf] = pw;
            }
        // P@V: sP written & read by the SAME wave only; per-wave LDS ops in-order
        __builtin_amdgcn_s_setprio(1);
        #pragma unroll
        for (int to = 0; to < 4; ++to) {
            #pragma unroll
            for (int kc = 0; kc < 64; kc += 32) {
                bf16x8 a  = ldfrag(&sP[wv * 16 + col][kc + quad * 8]);
                bf16x8 bb = ldfrag(&sVt[to * 16 + col][kc + quad * 8]);
                oacc[to] = __builtin_amdgcn_mfma_f32_16x16x32_bf16(a, bb, oacc[to], 0, 0, 0);
            }
        }
        __builtin_amdgcn_s_setprio(0);
    }

    // ---- epilogue: O -> concat hi/lo bf16 [B,S,D] ----
    #pragma unroll
    for (int to = 0; to < 4; ++to) {
        #pragma unroll
        for (int r = 0; r < 4; ++r) {
            const int qg = q0 + wv * 16 + quad * 4 + r;
            const size_t idx = ((size_t)b * S_ + qg) * D_ + h * DK_ + to * 16 + col;
            const float o = oacc[to][r];
            const unsigned short oh16 = f2bf(o);
            ch[idx] = oh16;
            cl[idx] = f2bf(o - bf2f(oh16));
        }
    }
}

// ---------------------------------------------------------------------------
extern "C" void kernel_launch(void* const* d_in, const int* in_sizes, int n_in,
                              void* d_out, int out_size, void* d_ws, size_t ws_size,
                              hipStream_t stream) {
    const float* q  = (const float*)d_in[0];
    const float* k  = (const float*)d_in[1];
    const float* v  = (const float*)d_in[2];
    const int* mask = (const int*)d_in[3];
    const float* Wq = (const float*)d_in[4];  const float* bq = (const float*)d_in[5];
    const float* Wk = (const float*)d_in[6];  const float* bk = (const float*)d_in[7];
    const float* Wv = (const float*)d_in[8];  const float* bv = (const float*)d_in[9];
    const float* Wo = (const float*)d_in[10]; const float* bo = (const float*)d_in[11];

    float* out    = (float*)d_out;                 // [B,S,D]
    float* scores = out + (size_t)B_ * S_ * D_;    // [B,H,S,S]

    const size_t NH = (size_t)B_ * H_ * S_ * DK_;  // 4.19M elems (== M_*D_)
    unsigned short* W = (unsigned short*)d_ws;
    unsigned short* q_hi = W + 0 * NH;
    unsigned short* q_lo = W + 1 * NH;
    unsigned short* k_hi = W + 2 * NH;
    unsigned short* k_lo = W + 3 * NH;
    unsigned short* v_hi = W + 4 * NH;
    // slots 7..12: X splits (live split->gemm_qkv); concat hi/lo aliases 7/8
    unsigned short* qXh = W + 7 * NH;  unsigned short* qXl = W + 8 * NH;
    unsigned short* kXh = W + 9 * NH;  unsigned short* kXl = W + 10 * NH;
    unsigned short* vXh = W + 11 * NH; unsigned short* vXl = W + 12 * NH;
    unsigned short* cat_h = qXh;       unsigned short* cat_l = qXl;   // reuse after gemm_qkv
    unsigned short* Wcat_h = W + 13 * NH;                 // [1536*512]
    unsigned short* Wcat_l = Wcat_h + 786432;
    unsigned short* Wo_h   = Wcat_l + 786432;             // [512*512]
    unsigned short* Wo_l   = Wo_h + 262144;
    unsigned long long* mbits = (unsigned long long*)(Wo_l + 262144);  // 2MB
    // ws use ~115 MB total

    split_x3<<<dim3(2048, 3), 256, 0, stream>>>(q, k, v, qXh, qXl, kXh, kXl, vXh, vXl);
    split_w4<<<dim3(128, 4), 256, 0, stream>>>(Wq, Wk, Wv, Wo, Wcat_h, Wcat_l, Wo_h, Wo_l);
    mask_pack<<<dim3(65536), 256, 0, stream>>>(mask, mbits);

    // fused QKV projections: N=1536, grid 64x12 = 768 blocks
    gemm_hl<<<dim3(64, 12), 256, 0, stream>>>(
        qXh, qXl, kXh, kXl, vXh, vXl, Wcat_h, Wcat_l, bq, bk, bv,
        nullptr, q_hi, q_lo, k_hi, k_lo, v_hi, 1);

    attn_mfma_kernel<<<dim3(S_ / 64, H_, B_), 256, 0, stream>>>(
        q_hi, q_lo, k_hi, k_lo, v_hi, mbits, scores, cat_h, cat_l);

    // output projection: N=512, fp32 out
    gemm_hl<<<dim3(64, 4), 256, 0, stream>>>(
        cat_h, cat_l, nullptr, nullptr, nullptr, nullptr, Wo_h, Wo_l, bo, nullptr, nullptr,
        out, nullptr, nullptr, nullptr, nullptr, nullptr, 0);
}

// Round 5
// 917.311 us; speedup vs baseline: 1.2854x; 1.0770x over previous
//
#include <hip/hip_runtime.h>
#include <hip/hip_bf16.h>

#define B_ 4
#define S_ 2048
#define D_ 512
#define H_ 8
#define DK_ 64
#define M_ (B_*S_)   // 8192 rows

typedef float f32x4 __attribute__((ext_vector_type(4)));
typedef __bf16 bf16x8 __attribute__((ext_vector_type(8)));
typedef unsigned short u16x8 __attribute__((ext_vector_type(8)));

static __device__ __forceinline__ unsigned short f2bf(float x) {
    return __builtin_bit_cast(unsigned short, __float2bfloat16(x));
}
static __device__ __forceinline__ float bf2f(unsigned short u) {
    return __bfloat162float(__builtin_bit_cast(__hip_bfloat16, u));
}
static __device__ __forceinline__ bf16x8 ldfrag(const unsigned short* p) {
    return __builtin_bit_cast(bf16x8, *(const u16x8*)p);
}

// LDS-only barrier: orders ds_write/ds_read across waves WITHOUT draining
// vmcnt (global stores/prefetch keep flowing). Single asm so nothing is
// scheduled between the waitcnt and the barrier.
static __device__ __forceinline__ void bar_lds() {
    asm volatile("s_waitcnt lgkmcnt(0)\n\ts_barrier" ::: "memory");
}

// async global->LDS, 16B per lane; LDS dest = wave-uniform base + lane*16
typedef __attribute__((address_space(1))) const unsigned int gu32;
typedef __attribute__((address_space(3))) unsigned int lu32;
static __device__ __forceinline__ void gl_lds16(const unsigned short* g, unsigned short* l) {
    __builtin_amdgcn_global_load_lds((gu32*)g, (lu32*)l, 16, 0, 0);
}

// split 8 fp32 -> hi (truncated bf16) / lo (bf16 of exact residual)
static __device__ __forceinline__ void split8(const float4 x0, const float4 x1,
                                              u16x8& h, u16x8& l) {
    float f[8] = {x0.x, x0.y, x0.z, x0.w, x1.x, x1.y, x1.z, x1.w};
    #pragma unroll
    for (int j = 0; j < 8; ++j) {
        const unsigned u = __builtin_bit_cast(unsigned, f[j]);
        h[j] = (unsigned short)(u >> 16);
        const float hf = __builtin_bit_cast(float, u & 0xFFFF0000u);
        l[j] = (unsigned short)(__builtin_bit_cast(unsigned, f[j] - hf) >> 16);
    }
}

// ---------------------------------------------------------------------------
// Prep: split q,k,v [8192x512] fp32 -> hi/lo bf16 (row-major preserved)
// ---------------------------------------------------------------------------
__global__ __launch_bounds__(256) void split_x3(
    const float* __restrict__ xq, const float* __restrict__ xk, const float* __restrict__ xv,
    unsigned short* __restrict__ qh, unsigned short* __restrict__ qlo,
    unsigned short* __restrict__ kh, unsigned short* __restrict__ klo,
    unsigned short* __restrict__ vh, unsigned short* __restrict__ vlo)
{
    const size_t t = (size_t)blockIdx.x * 256 + threadIdx.x;   // < 524288
    const int z = blockIdx.y;
    const float* in = z == 0 ? xq : z == 1 ? xk : xv;
    unsigned short* oh = z == 0 ? qh : z == 1 ? kh : vh;
    unsigned short* ol = z == 0 ? qlo : z == 1 ? klo : vlo;
    const float4* p = (const float4*)(in + t * 8);
    u16x8 hh, ll;
    split8(p[0], p[1], hh, ll);
    ((u16x8*)oh)[t] = hh;
    ((u16x8*)ol)[t] = ll;
}

// Prep: split Wq,Wk,Wv into concatenated [1536x512] hi/lo; Wo separate
__global__ __launch_bounds__(256) void split_w4(
    const float* __restrict__ Wq, const float* __restrict__ Wk,
    const float* __restrict__ Wv, const float* __restrict__ Wo,
    unsigned short* __restrict__ Wcat_h, unsigned short* __restrict__ Wcat_l,
    unsigned short* __restrict__ Wo_h, unsigned short* __restrict__ Wo_l)
{
    const size_t t = (size_t)blockIdx.x * 256 + threadIdx.x;   // < 32768
    const int z = blockIdx.y;
    const float* in = z == 0 ? Wq : z == 1 ? Wk : z == 2 ? Wv : Wo;
    unsigned short* oh = z < 3 ? Wcat_h + (size_t)z * 262144 : Wo_h;
    unsigned short* ol = z < 3 ? Wcat_l + (size_t)z * 262144 : Wo_l;
    const float4* p = (const float4*)(in + t * 8);
    u16x8 hh, ll;
    split8(p[0], p[1], hh, ll);
    ((u16x8*)oh)[t] = hh;
    ((u16x8*)ol)[t] = ll;
}

// Prep: pack mask int32 [B,S,S] -> bitmask u64 (bit j = mask!=0), 64 cols/word
__global__ __launch_bounds__(256) void mask_pack(
    const int* __restrict__ mask, unsigned long long* __restrict__ bits)
{
    const size_t t = (size_t)blockIdx.x * 256 + threadIdx.x;   // < B*S*S
    const int m = mask[t];
    const unsigned long long w = __ballot(m != 0);
    if ((threadIdx.x & 63) == 0) bits[t >> 6] = w;
}

// ---------------------------------------------------------------------------
// hi/lo-split MFMA GEMM v4: Y = X @ W^T + bias
//   Y ~= Xh@Wh + Xl@Wh + Xh@Wl (3 MFMAs per k-slice; dropped Xl@Wl ~ 2^-16)
// 128x128 tile, BK=32, 16 K-steps. Double-buffered LDS (64KB, 2 blocks/CU).
// T4 counted vmcnt: STAGE(t+2) issued after compute; at each step top we wait
// vmcnt(8) (= the next buffer's still-inflight loads) + raw s_barrier, so the
// prefetch stays in flight across the barrier (never drained to 0 mid-loop).
// LDS chunk-swizzle (rule 21 both-sides): gl_lds dest linear; global SOURCE
// pre-swizzled per 16B chunk; ds_read applies the same XOR.
// fused=1: QKV (N=1536, X selected per n-block, head-layout hi/lo out)
// fused=0: out-proj (N=512, fp32 out)
// ---------------------------------------------------------------------------
#define GBK 32
__global__ __launch_bounds__(256, 2) void gemm_hl(
    const unsigned short* __restrict__ qXh, const unsigned short* __restrict__ qXl,
    const unsigned short* __restrict__ kXh, const unsigned short* __restrict__ kXl,
    const unsigned short* __restrict__ vXh, const unsigned short* __restrict__ vXl,
    const unsigned short* __restrict__ Wh, const unsigned short* __restrict__ Wl,
    const float* __restrict__ b0, const float* __restrict__ b1, const float* __restrict__ b2,
    float* __restrict__ Yf32,
    unsigned short* __restrict__ q_hi, unsigned short* __restrict__ q_lo,
    unsigned short* __restrict__ k_hi, unsigned short* __restrict__ k_lo,
    unsigned short* __restrict__ v_hi, int fused)
{
    // [buf][arr][128*32] arr: 0=Ah 1=Al 2=Bh 3=Bl   (64 KB total)
    __shared__ __align__(16) unsigned short lds[2][4][128 * GBK];

    const int tid = threadIdx.x;
    const int lane = tid & 63, wv = tid >> 6;
    const int quad = lane >> 4, col = lane & 15;
    const int wm = wv >> 1, wn = wv & 1;
    const int m0 = blockIdx.x * 128;
    const int n0g = blockIdx.y * 128;
    const int mat = fused ? (n0g >> 9) : 0;   // block-uniform
    const unsigned short* Xh = (!fused || mat == 0) ? qXh : (mat == 1 ? kXh : vXh);
    const unsigned short* Xl = (!fused || mat == 0) ? qXl : (mat == 1 ? kXl : vXl);

    // staging lane map: 1024B gl_lds = 16 rows x 64B; lane l -> row l>>2,
    // LDS 16B slot l&3; source chunk pre-swizzled: (l&3) ^ ((l>>3)&3)
    const int rsub = lane >> 2;
    const int csw = (((lane & 3) ^ ((lane >> 3) & 3))) * 8;   // elem offset

    f32x4 acc[4][4] = {};

    auto STAGE = [&](int t, int buf) {
        const int kt = t * GBK;
        #pragma unroll
        for (int i = 0; i < 2; ++i) {
            const int r0 = wv * 32 + i * 16;           // wave-uniform row base
            gl_lds16(Xh + (size_t)(m0 + r0 + rsub) * D_ + kt + csw, &lds[buf][0][r0 * GBK]);
            gl_lds16(Xl + (size_t)(m0 + r0 + rsub) * D_ + kt + csw, &lds[buf][1][r0 * GBK]);
            gl_lds16(Wh + (size_t)(n0g + r0 + rsub) * D_ + kt + csw, &lds[buf][2][r0 * GBK]);
            gl_lds16(Wl + (size_t)(n0g + r0 + rsub) * D_ + kt + csw, &lds[buf][3][r0 * GBK]);
        }
    };

    auto COMPUTE = [&](int buf) {
        bf16x8 ah[4], al[4], bh[4], bl[4];
        #pragma unroll
        for (int i = 0; i < 4; ++i) {
            const int ra = wm * 64 + i * 16 + col;
            const int ca = (quad ^ ((ra >> 1) & 3)) * 8;   // swizzled chunk
            ah[i] = ldfrag(&lds[buf][0][ra * GBK + ca]);
            al[i] = ldfrag(&lds[buf][1][ra * GBK + ca]);
            const int rb = wn * 64 + i * 16 + col;
            const int cb = (quad ^ ((rb >> 1) & 3)) * 8;
            bh[i] = ldfrag(&lds[buf][2][rb * GBK + cb]);
            bl[i] = ldfrag(&lds[buf][3][rb * GBK + cb]);
        }
        __builtin_amdgcn_s_setprio(1);
        #pragma unroll
        for (int i = 0; i < 4; ++i)
            #pragma unroll
            for (int j = 0; j < 4; ++j) {
                acc[i][j] = __builtin_amdgcn_mfma_f32_16x16x32_bf16(ah[i], bh[j], acc[i][j], 0, 0, 0);
                acc[i][j] = __builtin_amdgcn_mfma_f32_16x16x32_bf16(al[i], bh[j], acc[i][j], 0, 0, 0);
                acc[i][j] = __builtin_amdgcn_mfma_f32_16x16x32_bf16(ah[i], bl[j], acc[i][j], 0, 0, 0);
            }
        __builtin_amdgcn_s_setprio(0);
    };

    STAGE(0, 0);
    STAGE(1, 1);
    int cur = 0;
    for (int t = 0; t < 16; ++t) {
        // buf(cur)'s 8 loads are the oldest; 8 newer (next buf) may stay in flight
        if (t < 15) asm volatile("s_waitcnt vmcnt(8)\n\ts_barrier" ::: "memory");
        else        asm volatile("s_waitcnt vmcnt(0)\n\ts_barrier" ::: "memory");
        COMPUTE(cur);
        asm volatile("s_barrier" ::: "memory");   // all waves done reading buf(cur)
        if (t < 14) STAGE(t + 2, cur);            // overwrite; stays in flight
        cur ^= 1;
    }

    // epilogue: C/D layout col=lane&15 (n), row=quad*4+r (m)
    #pragma unroll
    for (int j = 0; j < 4; ++j) {
        const int ng = n0g + wn * 64 + j * 16 + col;
        const int n = fused ? (ng & 511) : ng;
        const float bias = fused ? (mat == 0 ? b0[n] : mat == 1 ? b1[n] : b2[n]) : b0[n];
        #pragma unroll
        for (int i = 0; i < 4; ++i) {
            #pragma unroll
            for (int r = 0; r < 4; ++r) {
                const int m = m0 + wm * 64 + i * 16 + quad * 4 + r;
                const float vv = acc[i][j][r] + bias;
                if (!fused) {
                    Yf32[(size_t)m * D_ + n] = vv;
                } else {
                    const int bi = m >> 11, si = m & (S_ - 1);
                    const int hh = n >> 6, dk = n & 63;
                    const size_t idx = (((size_t)bi * H_ + hh) * S_ + si) * DK_ + dk;
                    const unsigned short hi = f2bf(vv);
                    if (mat == 0)      { q_hi[idx] = hi; q_lo[idx] = f2bf(vv - bf2f(hi)); }
                    else if (mat == 1) { k_hi[idx] = hi; k_lo[idx] = f2bf(vv - bf2f(hi)); }
                    else               { v_hi[idx] = hi; }
                }
            }
        }
    }
}

// ---------------------------------------------------------------------------
// Flash-style two-pass MFMA attention, v4:
//  - Q fragments in registers; mask as packed bitwords; T14 async K/V staging
//  - LDS-only barriers (lgkmcnt(0)+s_barrier): score stores and K/V prefetch
//    are never drained mid-loop -> stores pipeline across tiles
//  - nontemporal scores stores (537MB stream bypasses L2, keeps K/V cached)
//  - coalesced scores write via fp32 LDS tile aliased over dead K tile
//  - setprio(1) around MFMA clusters (T5)
// ---------------------------------------------------------------------------
__global__ __launch_bounds__(256) void attn_mfma_kernel(
    const unsigned short* __restrict__ q_hi, const unsigned short* __restrict__ q_lo,
    const unsigned short* __restrict__ k_hi, const unsigned short* __restrict__ k_lo,
    const unsigned short* __restrict__ v_hi, const unsigned long long* __restrict__ mbits,
    float* __restrict__ scores,
    unsigned short* __restrict__ ch, unsigned short* __restrict__ cl)
{
    // +8 pad (16B) keeps b128 alignment; row stride 144B -> 2-way bank alias (free)
    __shared__ __align__(16) unsigned short sK2[2][64][72];   // [0]=hi [1]=lo
    __shared__ __align__(16) unsigned short sVt[64][72];      // [dk][kpos]
    __shared__ __align__(16) unsigned short sP[64][72];       // [qrow][kpos]

    const int tid = threadIdx.x;
    const int q0 = blockIdx.x * 64;
    const int h = blockIdx.y, b = blockIdx.z;
    const size_t bh = (size_t)b * H_ + h;
    const int wv = tid >> 6, lane = tid & 63, quad = lane >> 4, col = lane & 15;
    const int sr = tid >> 2, sc = (tid & 3) * 16;   // staging row / col base

    // fp32 p-tile aliased over the (dead-after-QK^T) K-hi tile: 64*68*4 = 17.4KB
    float* sPF = (float*)&sK2[0][0][0];

    // ---- Q fragments in registers (A-operand: [lane&15=row][quad*8+j=k]) ----
    bf16x8 qh[2], ql[2];
    {
        const size_t qb = (bh * S_ + q0 + wv * 16 + col) * DK_;
        qh[0] = ldfrag(q_hi + qb + quad * 8);
        qh[1] = ldfrag(q_hi + qb + 32 + quad * 8);
        ql[0] = ldfrag(q_lo + qb + quad * 8);
        ql[1] = ldfrag(q_lo + qb + 32 + quad * 8);
    }

    const size_t mrow_base = ((size_t)b * S_ + q0 + wv * 16 + quad * 4) * (S_ / 64);

    // ---- register staging (T14) ----
    u16x8 rkh[2], rkl[2], rv[2];
    auto ld_k = [&](int kt) {
        const u16x8* gh = (const u16x8*)(k_hi + (bh * S_ + kt * 64 + sr) * DK_ + sc);
        const u16x8* gl = (const u16x8*)(k_lo + (bh * S_ + kt * 64 + sr) * DK_ + sc);
        rkh[0] = gh[0]; rkh[1] = gh[1]; rkl[0] = gl[0]; rkl[1] = gl[1];
    };
    auto ld_v = [&](int kt) {
        const u16x8* gv = (const u16x8*)(v_hi + (bh * S_ + kt * 64 + sr) * DK_ + sc);
        rv[0] = gv[0]; rv[1] = gv[1];
    };

    auto compute_svals = [&](const unsigned long long* mw, float sv[4][4]) {
        #pragma unroll
        for (int t = 0; t < 4; ++t) {
            f32x4 acc = {0.f, 0.f, 0.f, 0.f};
            __builtin_amdgcn_s_setprio(1);
            #pragma unroll
            for (int kci = 0; kci < 2; ++kci) {
                bf16x8 bhf = ldfrag(&sK2[0][t * 16 + col][kci * 32 + quad * 8]);
                bf16x8 blf = ldfrag(&sK2[1][t * 16 + col][kci * 32 + quad * 8]);
                acc = __builtin_amdgcn_mfma_f32_16x16x32_bf16(qh[kci], bhf, acc, 0, 0, 0);
                acc = __builtin_amdgcn_mfma_f32_16x16x32_bf16(qh[kci], blf, acc, 0, 0, 0);
                acc = __builtin_amdgcn_mfma_f32_16x16x32_bf16(ql[kci], bhf, acc, 0, 0, 0);
            }
            __builtin_amdgcn_s_setprio(0);
            #pragma unroll
            for (int r = 0; r < 4; ++r) {
                float s = acc[r] * 0.125f;
                if (!((mw[r] >> (t * 16 + col)) & 1ull)) s = -1e9f;
                sv[t][r] = s;
            }
        }
    };

    // ---- pass 1: row max & sum ----
    float m_run[4], l_run[4];
    #pragma unroll
    for (int r = 0; r < 4; ++r) { m_run[r] = -1e30f; l_run[r] = 0.f; }

    ld_k(0);
    for (int kt = 0; kt < 32; ++kt) {
        bar_lds();   // all waves done reading previous tile (LDS-only)
        *(u16x8*)&sK2[0][sr][sc] = rkh[0]; *(u16x8*)&sK2[0][sr][sc + 8] = rkh[1];
        *(u16x8*)&sK2[1][sr][sc] = rkl[0]; *(u16x8*)&sK2[1][sr][sc + 8] = rkl[1];
        bar_lds();
        if (kt < 31) ld_k(kt + 1);     // latency hides under compute
        unsigned long long mw[4];
        #pragma unroll
        for (int r = 0; r < 4; ++r) mw[r] = mbits[mrow_base + (size_t)r * (S_ / 64) + kt];
        float sv[4][4];
        compute_svals(mw, sv);
        #pragma unroll
        for (int r = 0; r < 4; ++r) {
            float tm = fmaxf(fmaxf(sv[0][r], sv[1][r]), fmaxf(sv[2][r], sv[3][r]));
            #pragma unroll
            for (int mm = 1; mm < 16; mm <<= 1) tm = fmaxf(tm, __shfl_xor(tm, mm));
            const float nm = fmaxf(m_run[r], tm);
            float ts = __expf(sv[0][r] - nm) + __expf(sv[1][r] - nm)
                     + __expf(sv[2][r] - nm) + __expf(sv[3][r] - nm);
            #pragma unroll
            for (int mm = 1; mm < 16; mm <<= 1) ts += __shfl_xor(ts, mm);
            l_run[r] = l_run[r] * __expf(m_run[r] - nm) + ts;
            m_run[r] = nm;
        }
    }
    float inv_l[4];
    #pragma unroll
    for (int r = 0; r < 4; ++r) inv_l[r] = 1.f / l_run[r];

    // ---- pass 2: recompute S, write scores (coalesced, nt), accumulate P@V ----
    f32x4 oacc[4] = {};
    ld_k(0); ld_v(0);
    for (int kt = 0; kt < 32; ++kt) {
        bar_lds();
        *(u16x8*)&sK2[0][sr][sc] = rkh[0]; *(u16x8*)&sK2[0][sr][sc + 8] = rkh[1];
        *(u16x8*)&sK2[1][sr][sc] = rkl[0]; *(u16x8*)&sK2[1][sr][sc + 8] = rkl[1];
        #pragma unroll
        for (int i = 0; i < 8; ++i) { sVt[sc + i][sr] = rv[0][i]; sVt[sc + 8 + i][sr] = rv[1][i]; }
        bar_lds();
        if (kt < 31) { ld_k(kt + 1); ld_v(kt + 1); }
        unsigned long long mw[4];
        #pragma unroll
        for (int r = 0; r < 4; ++r) mw[r] = mbits[mrow_base + (size_t)r * (S_ / 64) + kt];
        float sv[4][4];
        compute_svals(mw, sv);
        float pv[4][4];
        #pragma unroll
        for (int t = 0; t < 4; ++t) {
            #pragma unroll
            for (int r = 0; r < 4; ++r) {
                const float p = __expf(sv[t][r] - m_run[r]) * inv_l[r];
                pv[t][r] = p;
                sP[wv * 16 + quad * 4 + r][t * 16 + col] = f2bf(p);
            }
        }
        // K tile now dead for this iteration; all waves must be done reading it
        bar_lds();
        #pragma unroll
        for (int t = 0; t < 4; ++t)
            #pragma unroll
            for (int r = 0; r < 4; ++r)
                sPF[(wv * 16 + quad * 4 + r) * 68 + t * 16 + col] = pv[t][r];
        // coalesced nontemporal write: own 16 rows, 8 rows x 128B per instr
        #pragma unroll
        for (int rg = 0; rg < 2; ++rg)
            #pragma unroll
            for (int hf = 0; hf < 2; ++hf) {
                const int rl = wv * 16 + rg * 8 + (lane >> 3);
                const int cf = hf * 32 + (lane & 7) * 4;
                const f32x4 pw = *(const f32x4*)&sPF[rl * 68 + cf];
                __builtin_nontemporal_store(pw,
                    (f32x4*)&scores[(bh * S_ + q0 + rl) * S_ + kt * 64 + cf]);
            }
        // P@V: sP written & read by the SAME wave only; per-wave LDS ops in-order
        __builtin_amdgcn_s_setprio(1);
        #pragma unroll
        for (int to = 0; to < 4; ++to) {
            #pragma unroll
            for (int kc = 0; kc < 64; kc += 32) {
                bf16x8 a  = ldfrag(&sP[wv * 16 + col][kc + quad * 8]);
                bf16x8 bb = ldfrag(&sVt[to * 16 + col][kc + quad * 8]);
                oacc[to] = __builtin_amdgcn_mfma_f32_16x16x32_bf16(a, bb, oacc[to], 0, 0, 0);
            }
        }
        __builtin_amdgcn_s_setprio(0);
    }

    // ---- epilogue: O -> concat hi/lo bf16 [B,S,D] ----
    #pragma unroll
    for (int to = 0; to < 4; ++to) {
        #pragma unroll
        for (int r = 0; r < 4; ++r) {
            const int qg = q0 + wv * 16 + quad * 4 + r;
            const size_t idx = ((size_t)b * S_ + qg) * D_ + h * DK_ + to * 16 + col;
            const float o = oacc[to][r];
            const unsigned short oh16 = f2bf(o);
            ch[idx] = oh16;
            cl[idx] = f2bf(o - bf2f(oh16));
        }
    }
}

// ---------------------------------------------------------------------------
extern "C" void kernel_launch(void* const* d_in, const int* in_sizes, int n_in,
                              void* d_out, int out_size, void* d_ws, size_t ws_size,
                              hipStream_t stream) {
    const float* q  = (const float*)d_in[0];
    const float* k  = (const float*)d_in[1];
    const float* v  = (const float*)d_in[2];
    const int* mask = (const int*)d_in[3];
    const float* Wq = (const float*)d_in[4];  const float* bq = (const float*)d_in[5];
    const float* Wk = (const float*)d_in[6];  const float* bk = (const float*)d_in[7];
    const float* Wv = (const float*)d_in[8];  const float* bv = (const float*)d_in[9];
    const float* Wo = (const float*)d_in[10]; const float* bo = (const float*)d_in[11];

    float* out    = (float*)d_out;                 // [B,S,D]
    float* scores = out + (size_t)B_ * S_ * D_;    // [B,H,S,S]

    const size_t NH = (size_t)B_ * H_ * S_ * DK_;  // 4.19M elems (== M_*D_)
    unsigned short* W = (unsigned short*)d_ws;
    unsigned short* q_hi = W + 0 * NH;
    unsigned short* q_lo = W + 1 * NH;
    unsigned short* k_hi = W + 2 * NH;
    unsigned short* k_lo = W + 3 * NH;
    unsigned short* v_hi = W + 4 * NH;
    // slots 7..12: X splits (live split->gemm_qkv); concat hi/lo aliases 7/8
    unsigned short* qXh = W + 7 * NH;  unsigned short* qXl = W + 8 * NH;
    unsigned short* kXh = W + 9 * NH;  unsigned short* kXl = W + 10 * NH;
    unsigned short* vXh = W + 11 * NH; unsigned short* vXl = W + 12 * NH;
    unsigned short* cat_h = qXh;       unsigned short* cat_l = qXl;   // reuse after gemm_qkv
    unsigned short* Wcat_h = W + 13 * NH;                 // [1536*512]
    unsigned short* Wcat_l = Wcat_h + 786432;
    unsigned short* Wo_h   = Wcat_l + 786432;             // [512*512]
    unsigned short* Wo_l   = Wo_h + 262144;
    unsigned long long* mbits = (unsigned long long*)(Wo_l + 262144);  // 2MB
    // ws use ~115 MB total

    split_x3<<<dim3(2048, 3), 256, 0, stream>>>(q, k, v, qXh, qXl, kXh, kXl, vXh, vXl);
    split_w4<<<dim3(128, 4), 256, 0, stream>>>(Wq, Wk, Wv, Wo, Wcat_h, Wcat_l, Wo_h, Wo_l);
    mask_pack<<<dim3(65536), 256, 0, stream>>>(mask, mbits);

    // fused QKV projections: N=1536, grid 64x12 = 768 blocks
    gemm_hl<<<dim3(64, 12), 256, 0, stream>>>(
        qXh, qXl, kXh, kXl, vXh, vXl, Wcat_h, Wcat_l, bq, bk, bv,
        nullptr, q_hi, q_lo, k_hi, k_lo, v_hi, 1);

    attn_mfma_kernel<<<dim3(S_ / 64, H_, B_), 256, 0, stream>>>(
        q_hi, q_lo, k_hi, k_lo, v_hi, mbits, scores, cat_h, cat_l);

    // output projection: N=512, fp32 out
    gemm_hl<<<dim3(64, 4), 256, 0, stream>>>(
        cat_h, cat_l, nullptr, nullptr, nullptr, nullptr, Wo_h, Wo_l, bo, nullptr, nullptr,
        out, nullptr, nullptr, nullptr, nullptr, nullptr, 0);
}